// Round 4
// baseline (695.656 us; speedup 1.0000x reference)
//
#include <hip/hip_runtime.h>
#include <hip/hip_bf16.h>

#define N_NODES 100000
#define N_EDGES 1000000
#define D 64

// ---------------- degree (weighted by edge-type weight) ----------------
__global__ __launch_bounds__(256) void deg_kernel(
    const int* __restrict__ dst, const int* __restrict__ efeat,
    const float* __restrict__ edge_weight, float* __restrict__ deg) {
    int e = blockIdx.x * blockDim.x + threadIdx.x;
    if (e >= N_EDGES) return;
    int t = efeat[e] - 1;                  // 0..7
    float x = edge_weight[t] * 10.0f;
    float w = x > 0.0f ? x : 0.01f * x;    // leaky_relu, slope 0.01
    atomicAdd(&deg[dst[e]], w);
}

// ---------------- norm = rsqrt(clip(deg,1)) in-place ----------------
__global__ __launch_bounds__(256) void norm_kernel(float* __restrict__ deg) {
    int i = blockIdx.x * blockDim.x + threadIdx.x;
    if (i >= N_NODES) return;
    float d = deg[i];
    d = d < 1.0f ? 1.0f : d;
    deg[i] = rsqrtf(d);
}

// ---------------- spmm1: h1raw[d] += feats[s] * norm[s] --------------------
__global__ __launch_bounds__(256) void spmm1(
    const float* __restrict__ feats, const float* __restrict__ norm,
    const int* __restrict__ src, const int* __restrict__ dst,
    float* __restrict__ h1) {
    int e = blockIdx.x * 4 + (threadIdx.x >> 6);
    int lane = threadIdx.x & 63;
    if (e >= N_EDGES) return;
    int s = src[e];
    int d = dst[e];
    float v = feats[s * D + lane] * norm[s];
    atomicAdd(&h1[d * D + lane], v);
}

// ---------------- s1 snapshot: out[n,128+k] = norm[n]^2 * h1[n,k] ----------
// (f32, parked in the not-yet-final j=2 column block of d_out)
__global__ __launch_bounds__(256) void s1_kernel(
    const float* __restrict__ h1, const float* __restrict__ norm,
    float* __restrict__ out) {
    int i = blockIdx.x * blockDim.x + threadIdx.x;   // 0 .. N*64-1
    if (i >= N_NODES * D) return;
    int n = i >> 6;
    int k = i & 63;
    float ns = norm[n];
    out[n * 192 + 128 + k] = ns * ns * h1[i];
}

// ---------------- spmm2: h2raw[d] += s1[s]  (s1 lives in out cols 128..191)
__global__ __launch_bounds__(256) void spmm2(
    const float* __restrict__ outS1,
    const int* __restrict__ src, const int* __restrict__ dst,
    float* __restrict__ h2) {
    int e = blockIdx.x * 4 + (threadIdx.x >> 6);
    int lane = threadIdx.x & 63;
    if (e >= N_EDGES) return;
    int s = src[e];
    int d = dst[e];
    float v = outS1[s * 192 + 128 + lane];
    atomicAdd(&h2[d * D + lane], v);
}

// ---------------- GEMM: out[:, col_off : col_off+64] = (H ⊙ norm?) @ W -----
// H: N x 64 f32 row source. use_norm: multiply row n by norm[n].
// 32 nodes per block, W and H staged in LDS, f32 accumulate, f32 store.
__global__ __launch_bounds__(256) void gemm_kernel(
    const float* __restrict__ H, const float* __restrict__ W,
    const float* __restrict__ norm, int use_norm, int col_off,
    float* __restrict__ out) {
    __shared__ float wt[D][D];   // wt[k][col]
    __shared__ float ht[32][D];  // ht[node_local][k]

    const int tid = threadIdx.x;
    const int node0 = blockIdx.x * 32;

    for (int i = tid; i < D * D; i += 256)
        ((float*)wt)[i] = W[i];

    for (int i = tid; i < 32 * D; i += 256) {
        int n = i >> 6;
        int k = i & 63;
        int node = node0 + n;
        float v = 0.0f;
        if (node < N_NODES) {
            v = H[node * D + k];
            if (use_norm) v *= norm[node];
        }
        ht[n][k] = v;
    }
    __syncthreads();

    const int col = tid & 63;
    const int nb = tid >> 6;   // wave id 0..3 -> nodes nb*8 .. nb*8+7
    float acc[8];
#pragma unroll
    for (int r = 0; r < 8; r++) acc[r] = 0.0f;

    for (int k = 0; k < D; k++) {
        float wv = wt[k][col];
#pragma unroll
        for (int r = 0; r < 8; r++)
            acc[r] += ht[nb * 8 + r][k] * wv;
    }

#pragma unroll
    for (int r = 0; r < 8; r++) {
        int node = node0 + nb * 8 + r;
        if (node < N_NODES)
            out[node * 192 + col_off + col] = acc[r];
    }
}

extern "C" void kernel_launch(void* const* d_in, const int* in_sizes, int n_in,
                              void* d_out, int out_size, void* d_ws, size_t ws_size,
                              hipStream_t stream) {
    const float* feats = (const float*)d_in[0];
    const float* ew    = (const float*)d_in[1];
    const float* w0    = (const float*)d_in[2];
    const float* w1    = (const float*)d_in[3];
    const float* w2    = (const float*)d_in[4];
    const int* src   = (const int*)d_in[5];
    const int* dst   = (const int*)d_in[6];
    const int* efeat = (const int*)d_in[7];
    float* out = (float*)d_out;

    // ws layout (peak 26.0 MB): deg/norm [100000 f32] | hbuf [6.4M f32]
    // hbuf holds h1raw first, then (after f32 snapshot into d_out) h2raw.
    float* deg  = (float*)d_ws;
    float* hbuf = deg + N_NODES;
    const size_t HBYTES = sizeof(float) * (size_t)N_NODES * D;  // 25.6 MB

    // zero deg + hbuf (26.0 MB)
    hipMemsetAsync(d_ws, 0, sizeof(float) * N_NODES + HBYTES, stream);

    deg_kernel<<<(N_EDGES + 255) / 256, 256, 0, stream>>>(dst, efeat, ew, deg);
    norm_kernel<<<(N_NODES + 255) / 256, 256, 0, stream>>>(deg);

    // h1raw[d] += feats[s] * norm[s]
    spmm1<<<(N_EDGES + 3) / 4, 256, 0, stream>>>(feats, deg, src, dst, hbuf);

    // out cols 0..63  = feats @ w0
    gemm_kernel<<<(N_NODES + 31) / 32, 256, 0, stream>>>(feats, w0, deg, 0, 0, out);
    // out cols 64..127 = (h1raw * norm) @ w1
    gemm_kernel<<<(N_NODES + 31) / 32, 256, 0, stream>>>(hbuf, w1, deg, 1, 64, out);

    // snapshot s1 = norm^2 * h1raw into out cols 128..191 (f32)
    s1_kernel<<<(N_NODES * D + 255) / 256, 256, 0, stream>>>(hbuf, deg, out);

    // reuse hbuf as h2raw
    hipMemsetAsync(hbuf, 0, HBYTES, stream);

    // h2raw[d] += s1[s]
    spmm2<<<(N_EDGES + 3) / 4, 256, 0, stream>>>(out, src, dst, hbuf);

    // out cols 128..191 = (h2raw * norm) @ w2   (overwrites s1)
    gemm_kernel<<<(N_NODES + 31) / 32, 256, 0, stream>>>(hbuf, w2, deg, 1, 128, out);
}

// Round 5
// 651.214 us; speedup vs baseline: 1.0682x; 1.0682x over previous
//
#include <hip/hip_runtime.h>

#define N_NODES 100000
#define N_EDGES 1000000
#define D 64
#define SCAN_T 1024

// ---- fused weighted-degree + in-degree histogram (1M edges, 2 atomics/edge)
__global__ __launch_bounds__(256) void hist_deg_kernel(
    const int* __restrict__ dst, const int* __restrict__ efeat,
    const float* __restrict__ edge_weight,
    float* __restrict__ deg, int* __restrict__ cnt) {
    int e = blockIdx.x * blockDim.x + threadIdx.x;
    if (e >= N_EDGES) return;
    int d = dst[e];
    int t = efeat[e] - 1;                  // 0..7
    float x = edge_weight[t] * 10.0f;
    float w = x > 0.0f ? x : 0.01f * x;    // leaky_relu, slope 0.01
    atomicAdd(&deg[d], w);
    atomicAdd(&cnt[d], 1);
}

// ---- norm = rsqrt(clip(deg,1)) in-place ----
__global__ __launch_bounds__(256) void norm_kernel(float* __restrict__ deg) {
    int i = blockIdx.x * blockDim.x + threadIdx.x;
    if (i >= N_NODES) return;
    float d = deg[i];
    d = d < 1.0f ? 1.0f : d;
    deg[i] = rsqrtf(d);
}

// ---- exclusive scan of cnt -> row_start[N+1], cursor (single 1024-thr block)
__global__ __launch_bounds__(SCAN_T) void scan_kernel(
    const int* __restrict__ cnt, int* __restrict__ row_start,
    int* __restrict__ cursor) {
    __shared__ int lds[SCAN_T];
    const int tid = threadIdx.x;
    int carry = 0;
    for (int base = 0; base < N_NODES; base += SCAN_T) {
        int i = base + tid;
        int v = (i < N_NODES) ? cnt[i] : 0;
        lds[tid] = v;
        __syncthreads();
        for (int off = 1; off < SCAN_T; off <<= 1) {
            int add = (tid >= off) ? lds[tid - off] : 0;
            __syncthreads();
            lds[tid] += add;
            __syncthreads();
        }
        int incl = lds[tid];
        if (i < N_NODES) {
            int ex = carry + incl - v;     // exclusive
            row_start[i] = ex;
            cursor[i] = ex;
        }
        carry += lds[SCAN_T - 1];          // chunk total (stable after loop)
        __syncthreads();                   // protect lds before next chunk
    }
    if (tid == 0) row_start[N_NODES] = carry;   // == N_EDGES
}

// ---- scatter edges into CSR (order within a row irrelevant) ----
__global__ __launch_bounds__(256) void fill_csr_kernel(
    const int* __restrict__ src, const int* __restrict__ dst,
    int* __restrict__ cursor, int* __restrict__ csr_src) {
    int e = blockIdx.x * blockDim.x + threadIdx.x;
    if (e >= N_EDGES) return;
    int pos = atomicAdd(&cursor[dst[e]], 1);
    csr_src[pos] = src[e];
}

// ---- gather-SpMM: out[n*192+col_off+lane] = sum_{e in row(n)} H[s_e]*norm[s_e]^POW
// one wave per destination node; lane = feature; registers accumulate; plain store.
template <int POW>
__global__ __launch_bounds__(256) void spmm_csr(
    const float* __restrict__ H, int ldh,
    const float* __restrict__ norm,
    const int* __restrict__ row_start, const int* __restrict__ csr_src,
    float* __restrict__ out, int col_off) {
    int node = blockIdx.x * 4 + (threadIdx.x >> 6);
    int lane = threadIdx.x & 63;
    if (node >= N_NODES) return;
    int beg = row_start[node];
    int end = row_start[node + 1];
    float acc = 0.0f;
    int e = beg;
    for (; e + 1 < end; e += 2) {          // 2 independent gathers in flight
        int s0 = csr_src[e];
        int s1 = csr_src[e + 1];
        float n0 = norm[s0];
        float n1 = norm[s1];
        if (POW == 2) { n0 *= n0; n1 *= n1; }
        float v0 = H[(size_t)s0 * ldh + lane];
        float v1 = H[(size_t)s1 * ldh + lane];
        acc = fmaf(v0, n0, acc);
        acc = fmaf(v1, n1, acc);
    }
    if (e < end) {
        int s0 = csr_src[e];
        float n0 = norm[s0];
        if (POW == 2) n0 *= n0;
        acc = fmaf(H[(size_t)s0 * ldh + lane], n0, acc);
    }
    out[(size_t)node * 192 + col_off + lane] = acc;
}

// ---- GEMM: out[:, col_off:col_off+64] = (H ⊙ norm?) @ W ----
// In-place safe when H aliases the written column block: each block stages its
// own 32 rows into LDS (reads) before __syncthreads, then writes the same rows.
__global__ __launch_bounds__(256) void gemm_kernel(
    const float* __restrict__ H, int ldh,
    const float* __restrict__ W,
    const float* __restrict__ norm, int use_norm, int col_off,
    float* __restrict__ out) {
    __shared__ float wt[D][D];   // wt[k][col]
    __shared__ float ht[32][D];  // ht[node_local][k]

    const int tid = threadIdx.x;
    const int node0 = blockIdx.x * 32;

    for (int i = tid; i < D * D; i += 256)
        ((float*)wt)[i] = W[i];

    for (int i = tid; i < 32 * D; i += 256) {
        int n = i >> 6;
        int k = i & 63;
        int node = node0 + n;
        float v = 0.0f;
        if (node < N_NODES) {
            v = H[(size_t)node * ldh + k];
            if (use_norm) v *= norm[node];
        }
        ht[n][k] = v;
    }
    __syncthreads();

    const int col = tid & 63;
    const int nb = tid >> 6;
    float acc[8];
#pragma unroll
    for (int r = 0; r < 8; r++) acc[r] = 0.0f;

    for (int k = 0; k < D; k++) {
        float wv = wt[k][col];
#pragma unroll
        for (int r = 0; r < 8; r++)
            acc[r] += ht[nb * 8 + r][k] * wv;
    }

#pragma unroll
    for (int r = 0; r < 8; r++) {
        int node = node0 + nb * 8 + r;
        if (node < N_NODES)
            out[(size_t)node * 192 + col_off + col] = acc[r];
    }
}

extern "C" void kernel_launch(void* const* d_in, const int* in_sizes, int n_in,
                              void* d_out, int out_size, void* d_ws, size_t ws_size,
                              hipStream_t stream) {
    const float* feats = (const float*)d_in[0];
    const float* ew    = (const float*)d_in[1];
    const float* w0    = (const float*)d_in[2];
    const float* w1    = (const float*)d_in[3];
    const float* w2    = (const float*)d_in[4];
    const int* src   = (const int*)d_in[5];
    const int* dst   = (const int*)d_in[6];
    const int* efeat = (const int*)d_in[7];
    float* out = (float*)d_out;

    // ws layout (5.6 MB total): deg[N] f32 | cnt[N] | row_start[N+1] | cursor[N] | csr_src[1M]
    float* deg     = (float*)d_ws;
    int* cnt       = (int*)(deg + N_NODES);
    int* row_start = cnt + N_NODES;
    int* cursor    = row_start + N_NODES + 1;
    int* csr_src   = cursor + N_NODES;

    // zero deg + cnt only (0.8 MB)
    hipMemsetAsync(d_ws, 0, sizeof(float) * 2 * N_NODES, stream);

    hist_deg_kernel<<<(N_EDGES + 255) / 256, 256, 0, stream>>>(dst, efeat, ew, deg, cnt);
    norm_kernel<<<(N_NODES + 255) / 256, 256, 0, stream>>>(deg);
    scan_kernel<<<1, SCAN_T, 0, stream>>>(cnt, row_start, cursor);
    fill_csr_kernel<<<(N_EDGES + 255) / 256, 256, 0, stream>>>(src, dst, cursor, csr_src);

    // h1raw -> out cols 64..127:  h1raw[d] = sum feats[s]*norm[s]
    spmm_csr<1><<<(N_NODES + 3) / 4, 256, 0, stream>>>(
        feats, D, deg, row_start, csr_src, out, 64);
    // h2raw -> out cols 128..191: h2raw[d] = sum h1raw[s]*norm[s]^2
    spmm_csr<2><<<(N_NODES + 3) / 4, 256, 0, stream>>>(
        out + 64, 192, deg, row_start, csr_src, out, 128);

    // out cols 0..63   = feats @ w0
    gemm_kernel<<<(N_NODES + 31) / 32, 256, 0, stream>>>(feats, D, w0, deg, 0, 0, out);
    // out cols 64..127 = (h1raw*norm) @ w1   (in place)
    gemm_kernel<<<(N_NODES + 31) / 32, 256, 0, stream>>>(out + 64, 192, w1, deg, 1, 64, out);
    // out cols 128..191= (h2raw*norm) @ w2   (in place)
    gemm_kernel<<<(N_NODES + 31) / 32, 256, 0, stream>>>(out + 128, 192, w2, deg, 1, 128, out);
}

// Round 6
// 482.083 us; speedup vs baseline: 1.4430x; 1.3508x over previous
//
#include <hip/hip_runtime.h>

#define N_NODES 100000
#define N_EDGES 1000000
#define D 64

// ---- fused weighted-degree + in-degree histogram (1M edges, 2 atomics/edge)
__global__ __launch_bounds__(256) void hist_deg_kernel(
    const int* __restrict__ dst, const int* __restrict__ efeat,
    const float* __restrict__ edge_weight,
    float* __restrict__ deg, int* __restrict__ cnt) {
    int e = blockIdx.x * blockDim.x + threadIdx.x;
    if (e >= N_EDGES) return;
    int d = dst[e];
    int t = efeat[e] - 1;                  // 0..7
    float x = edge_weight[t] * 10.0f;
    float w = x > 0.0f ? x : 0.01f * x;    // leaky_relu, slope 0.01
    atomicAdd(&deg[d], w);
    atomicAdd(&cnt[d], 1);
}

// ---- per-block CSR range allocation + fused norm -------------------------
// Row ranges need only be DISJOINT, not ordered: each block scans its 1024
// counts in LDS, grabs a base via one atomicAdd on a global cursor, and
// writes row_start/cursor. Also folds norm = rsqrt(clip(deg,1)) in-place.
__global__ __launch_bounds__(1024) void alloc_norm_kernel(
    const int* __restrict__ cnt, float* __restrict__ deg,
    int* __restrict__ row_start, int* __restrict__ cursor,
    int* __restrict__ total) {
    __shared__ int lds[1024];
    __shared__ int base_s;
    const int tid = threadIdx.x;
    const int i = blockIdx.x * 1024 + tid;
    int v = (i < N_NODES) ? cnt[i] : 0;
    lds[tid] = v;
    __syncthreads();
    for (int off = 1; off < 1024; off <<= 1) {
        int add = (tid >= off) ? lds[tid - off] : 0;
        __syncthreads();
        lds[tid] += add;
        __syncthreads();
    }
    if (tid == 1023) base_s = atomicAdd(total, lds[1023]);
    __syncthreads();
    if (i < N_NODES) {
        int ex = base_s + lds[tid] - v;    // exclusive within block + base
        row_start[i] = ex;
        cursor[i] = ex;
        float d = deg[i];
        d = d < 1.0f ? 1.0f : d;
        deg[i] = rsqrtf(d);
    }
}

// ---- scatter edges into CSR (order within a row irrelevant) ----
__global__ __launch_bounds__(256) void fill_csr_kernel(
    const int* __restrict__ src, const int* __restrict__ dst,
    int* __restrict__ cursor, int* __restrict__ csr_src) {
    int e = blockIdx.x * blockDim.x + threadIdx.x;
    if (e >= N_EDGES) return;
    int pos = atomicAdd(&cursor[dst[e]], 1);
    csr_src[pos] = src[e];
}

// ---- gather-SpMM: out[n*192+col_off+lane] = sum_{e in row(n)} H[s_e]*norm[s_e]^POW
// one wave per destination node; lane = feature; registers accumulate; plain store.
template <int POW>
__global__ __launch_bounds__(256) void spmm_csr(
    const float* __restrict__ H, int ldh,
    const float* __restrict__ norm,
    const int* __restrict__ row_start, const int* __restrict__ cnt,
    const int* __restrict__ csr_src,
    float* __restrict__ out, int col_off) {
    int node = blockIdx.x * 4 + (threadIdx.x >> 6);
    int lane = threadIdx.x & 63;
    if (node >= N_NODES) return;
    int beg = row_start[node];
    int end = beg + cnt[node];
    float acc = 0.0f;
    int e = beg;
    for (; e + 1 < end; e += 2) {          // 2 independent gathers in flight
        int s0 = csr_src[e];
        int s1 = csr_src[e + 1];
        float n0 = norm[s0];
        float n1 = norm[s1];
        if (POW == 2) { n0 *= n0; n1 *= n1; }
        float v0 = H[(size_t)s0 * ldh + lane];
        float v1 = H[(size_t)s1 * ldh + lane];
        acc = fmaf(v0, n0, acc);
        acc = fmaf(v1, n1, acc);
    }
    if (e < end) {
        int s0 = csr_src[e];
        float n0 = norm[s0];
        if (POW == 2) n0 *= n0;
        acc = fmaf(H[(size_t)s0 * ldh + lane], n0, acc);
    }
    out[(size_t)node * 192 + col_off + lane] = acc;
}

// ---- GEMM: out[:, col_off:col_off+64] = (H ⊙ norm?) @ W ----
// In-place safe when H aliases the written column block: each block stages its
// own 32 rows into LDS (reads) before __syncthreads, then writes the same rows.
__global__ __launch_bounds__(256) void gemm_kernel(
    const float* __restrict__ H, int ldh,
    const float* __restrict__ W,
    const float* __restrict__ norm, int use_norm, int col_off,
    float* __restrict__ out) {
    __shared__ float wt[D][D];   // wt[k][col]
    __shared__ float ht[32][D];  // ht[node_local][k]

    const int tid = threadIdx.x;
    const int node0 = blockIdx.x * 32;

    for (int i = tid; i < D * D; i += 256)
        ((float*)wt)[i] = W[i];

    for (int i = tid; i < 32 * D; i += 256) {
        int n = i >> 6;
        int k = i & 63;
        int node = node0 + n;
        float v = 0.0f;
        if (node < N_NODES) {
            v = H[(size_t)node * ldh + k];
            if (use_norm) v *= norm[node];
        }
        ht[n][k] = v;
    }
    __syncthreads();

    const int col = tid & 63;
    const int nb = tid >> 6;
    float acc[8];
#pragma unroll
    for (int r = 0; r < 8; r++) acc[r] = 0.0f;

    for (int k = 0; k < D; k++) {
        float wv = wt[k][col];
#pragma unroll
        for (int r = 0; r < 8; r++)
            acc[r] += ht[nb * 8 + r][k] * wv;
    }

#pragma unroll
    for (int r = 0; r < 8; r++) {
        int node = node0 + nb * 8 + r;
        if (node < N_NODES)
            out[(size_t)node * 192 + col_off + col] = acc[r];
    }
}

extern "C" void kernel_launch(void* const* d_in, const int* in_sizes, int n_in,
                              void* d_out, int out_size, void* d_ws, size_t ws_size,
                              hipStream_t stream) {
    const float* feats = (const float*)d_in[0];
    const float* ew    = (const float*)d_in[1];
    const float* w0    = (const float*)d_in[2];
    const float* w1    = (const float*)d_in[3];
    const float* w2    = (const float*)d_in[4];
    const int* src   = (const int*)d_in[5];
    const int* dst   = (const int*)d_in[6];
    const int* efeat = (const int*)d_in[7];
    float* out = (float*)d_out;

    // ws layout (5.6 MB): deg[N] f32 | cnt[N] | total[1] | row_start[N] | cursor[N] | csr_src[1M]
    float* deg     = (float*)d_ws;
    int* cnt       = (int*)(deg + N_NODES);
    int* total     = cnt + N_NODES;
    int* row_start = total + 1;
    int* cursor    = row_start + N_NODES;
    int* csr_src   = cursor + N_NODES;

    // zero deg + cnt + total (0.8 MB)
    hipMemsetAsync(d_ws, 0, sizeof(float) * (2 * N_NODES + 1), stream);

    hist_deg_kernel<<<(N_EDGES + 255) / 256, 256, 0, stream>>>(dst, efeat, ew, deg, cnt);
    alloc_norm_kernel<<<(N_NODES + 1023) / 1024, 1024, 0, stream>>>(
        cnt, deg, row_start, cursor, total);
    fill_csr_kernel<<<(N_EDGES + 255) / 256, 256, 0, stream>>>(src, dst, cursor, csr_src);

    // h1raw -> out cols 64..127:  h1raw[d] = sum feats[s]*norm[s]
    spmm_csr<1><<<(N_NODES + 3) / 4, 256, 0, stream>>>(
        feats, D, deg, row_start, cnt, csr_src, out, 64);
    // h2raw -> out cols 128..191: h2raw[d] = sum h1raw[s]*norm[s]^2
    spmm_csr<2><<<(N_NODES + 3) / 4, 256, 0, stream>>>(
        out + 64, 192, deg, row_start, cnt, csr_src, out, 128);

    // out cols 0..63   = feats @ w0
    gemm_kernel<<<(N_NODES + 31) / 32, 256, 0, stream>>>(feats, D, w0, deg, 0, 0, out);
    // out cols 64..127 = (h1raw*norm) @ w1   (in place)
    gemm_kernel<<<(N_NODES + 31) / 32, 256, 0, stream>>>(out + 64, 192, w1, deg, 1, 64, out);
    // out cols 128..191= (h2raw*norm) @ w2   (in place)
    gemm_kernel<<<(N_NODES + 31) / 32, 256, 0, stream>>>(out + 128, 192, w2, deg, 1, 128, out);
}

// Round 7
// 472.486 us; speedup vs baseline: 1.4723x; 1.0203x over previous
//
#include <hip/hip_runtime.h>

#define N_NODES 100000
#define N_EDGES 1000000
#define D 64

// ---- histogram: ONE packed 64-bit atomic per edge ------------------------
// bits [63:40] = edge count, bits [39:0] = fixed-point sum of (w + 8) * 2^20
// (w+8 > 0 always: w = leaky_relu(ew*10) is bounded well inside (-8, 2^19))
__global__ __launch_bounds__(256) void hist_kernel(
    const int* __restrict__ dst, const int* __restrict__ efeat,
    const float* __restrict__ edge_weight,
    unsigned long long* __restrict__ dc) {
    int e = blockIdx.x * 256 + threadIdx.x;
    if (e >= N_EDGES) return;
    int d = dst[e];
    int t = efeat[e] - 1;                  // 0..7
    float x = edge_weight[t] * 10.0f;
    float w = x > 0.0f ? x : 0.01f * x;    // leaky_relu, slope 0.01
    unsigned long long fx =
        (unsigned long long)__float2uint_rn((w + 8.0f) * 1048576.0f);
    atomicAdd(&dc[d], (1ull << 40) | fx);
}

// ---- unpack dc -> norm/cnt, allocate disjoint CSR ranges per block -------
// Ranges need only be DISJOINT, not ordered: local LDS scan + one atomicAdd
// on a global cursor per 1024-node block.
__global__ __launch_bounds__(1024) void alloc_norm_kernel(
    const unsigned long long* __restrict__ dc,
    float* __restrict__ norm, int* __restrict__ cnt,
    int* __restrict__ row_start, int* __restrict__ cursor,
    int* __restrict__ total) {
    __shared__ int lds[1024];
    __shared__ int base_s;
    const int tid = threadIdx.x;
    const int i = blockIdx.x * 1024 + tid;
    int v = 0;
    if (i < N_NODES) {
        unsigned long long p = dc[i];
        v = (int)(p >> 40);
        float deg = (float)(p & ((1ull << 40) - 1)) * (1.0f / 1048576.0f)
                    - 8.0f * (float)v;
        deg = deg < 1.0f ? 1.0f : deg;
        norm[i] = rsqrtf(deg);
        cnt[i] = v;
    }
    lds[tid] = v;
    __syncthreads();
    for (int off = 1; off < 1024; off <<= 1) {
        int add = (tid >= off) ? lds[tid - off] : 0;
        __syncthreads();
        lds[tid] += add;
        __syncthreads();
    }
    if (tid == 1023) base_s = atomicAdd(total, lds[1023]);
    __syncthreads();
    if (i < N_NODES) {
        int ex = base_s + lds[tid] - v;    // block-exclusive + global base
        row_start[i] = ex;
        cursor[i] = ex;
    }
}

// ---- scatter edges into CSR (order within a row irrelevant) ----
__global__ __launch_bounds__(256) void fill_csr_kernel(
    const int* __restrict__ src, const int* __restrict__ dst,
    int* __restrict__ cursor, int* __restrict__ csr_src) {
    int e = blockIdx.x * 256 + threadIdx.x;
    if (e >= N_EDGES) return;
    int pos = atomicAdd(&cursor[dst[e]], 1);
    csr_src[pos] = src[e];
}

// ---- fused gather-SpMM + GEMM epilogue -----------------------------------
// One wave per destination node (grid exact: 25000 blocks x 4 waves).
// acc = sum_{e in row} H[s_e]*norm[s_e]^POW   (lane = feature k)
// optional raw save (spmm2's gather source), then out_row = (acc*norm) @ W.
template <int POW>
__global__ __launch_bounds__(256) void spmm_gemm(
    const float* __restrict__ H, int ldh,
    const float* __restrict__ norm,
    const int* __restrict__ row_start, const int* __restrict__ cnt,
    const int* __restrict__ csr_src,
    const float* __restrict__ W,
    float* __restrict__ h_save,          // nullptr: don't save raw row
    float* __restrict__ out, int col_off) {
    __shared__ float wt[D * D];          // wt[k*D + col]
    __shared__ float hs[4][D];
    const int tid = threadIdx.x;
    const int wv = tid >> 6;
    const int lane = tid & 63;
    const int node = blockIdx.x * 4 + wv;

    for (int i = tid; i < D * D; i += 256) wt[i] = W[i];

    int beg = row_start[node];
    int end = beg + cnt[node];
    float acc = 0.0f;
    int e = beg;
    for (; e + 1 < end; e += 2) {        // 2 independent gathers in flight
        int s0 = csr_src[e];
        int s1 = csr_src[e + 1];
        float n0 = norm[s0];
        float n1 = norm[s1];
        if (POW == 2) { n0 *= n0; n1 *= n1; }
        float v0 = H[(size_t)s0 * ldh + lane];
        float v1 = H[(size_t)s1 * ldh + lane];
        acc = fmaf(v0, n0, acc);
        acc = fmaf(v1, n1, acc);
    }
    if (e < end) {
        int s0 = csr_src[e];
        float n0 = norm[s0];
        if (POW == 2) n0 *= n0;
        acc = fmaf(H[(size_t)s0 * ldh + lane], n0, acc);
    }
    if (h_save) h_save[(size_t)node * D + lane] = acc;
    hs[wv][lane] = acc * norm[node];     // dst-side norm folded here
    __syncthreads();                     // covers wt (cross-wave) + hs

    float o = 0.0f;
#pragma unroll 8
    for (int k = 0; k < D; k++)
        o = fmaf(hs[wv][k], wt[k * D + lane], o);   // hs broadcast, wt 2-way
    out[(size_t)node * 192 + col_off + lane] = o;
}

// ---- plain GEMM for j=0: out[:,0:64] = feats @ W0 ----
__global__ __launch_bounds__(256) void gemm_kernel(
    const float* __restrict__ H,
    const float* __restrict__ W,
    float* __restrict__ out) {
    __shared__ float wt[D][D];   // wt[k][col]
    __shared__ float ht[32][D];  // ht[node_local][k]

    const int tid = threadIdx.x;
    const int node0 = blockIdx.x * 32;

    for (int i = tid; i < D * D; i += 256)
        ((float*)wt)[i] = W[i];

    for (int i = tid; i < 32 * D; i += 256) {
        int n = i >> 6;
        int k = i & 63;
        int node = node0 + n;
        ht[n][k] = (node < N_NODES) ? H[(size_t)node * D + k] : 0.0f;
    }
    __syncthreads();

    const int col = tid & 63;
    const int nb = tid >> 6;
    float acc[8];
#pragma unroll
    for (int r = 0; r < 8; r++) acc[r] = 0.0f;

    for (int k = 0; k < D; k++) {
        float wv = wt[k][col];
#pragma unroll
        for (int r = 0; r < 8; r++)
            acc[r] += ht[nb * 8 + r][k] * wv;
    }

#pragma unroll
    for (int r = 0; r < 8; r++) {
        int node = node0 + nb * 8 + r;
        if (node < N_NODES)
            out[(size_t)node * 192 + col] = acc[r];
    }
}

extern "C" void kernel_launch(void* const* d_in, const int* in_sizes, int n_in,
                              void* d_out, int out_size, void* d_ws, size_t ws_size,
                              hipStream_t stream) {
    const float* feats = (const float*)d_in[0];
    const float* ew    = (const float*)d_in[1];
    const float* w0    = (const float*)d_in[2];
    const float* w1    = (const float*)d_in[3];
    const float* w2    = (const float*)d_in[4];
    const int* src   = (const int*)d_in[5];
    const int* dst   = (const int*)d_in[6];
    const int* efeat = (const int*)d_in[7];
    float* out = (float*)d_out;

    // ws layout (~31 MB):
    // dc[N] u64 | total[1]+pad | norm[N] f32 | cnt[N] | row_start[N] | cursor[N]
    // | csr_src[1M] | h1raw[N*64] f32
    unsigned long long* dc = (unsigned long long*)d_ws;
    int* total     = (int*)(dc + N_NODES);             // [2 ints of pad space]
    float* norm    = (float*)(total + 2);
    int* cnt       = (int*)(norm + N_NODES);
    int* row_start = cnt + N_NODES;
    int* cursor    = row_start + N_NODES;
    int* csr_src   = cursor + N_NODES;
    float* h1raw   = (float*)(csr_src + N_EDGES);

    // zero dc + total only (~800 KB)
    hipMemsetAsync(d_ws, 0, sizeof(unsigned long long) * N_NODES + 8, stream);

    hist_kernel<<<(N_EDGES + 255) / 256, 256, 0, stream>>>(dst, efeat, ew, dc);
    alloc_norm_kernel<<<(N_NODES + 1023) / 1024, 1024, 0, stream>>>(
        dc, norm, cnt, row_start, cursor, total);
    fill_csr_kernel<<<(N_EDGES + 255) / 256, 256, 0, stream>>>(src, dst, cursor, csr_src);

    // cols 64..127 = (norm ⊙ A(norm ⊙ feats)) @ W1, saving h1raw = A(norm ⊙ feats)
    spmm_gemm<1><<<N_NODES / 4, 256, 0, stream>>>(
        feats, D, norm, row_start, cnt, csr_src, w1, h1raw, out, 64);
    // cols 128..191 = (norm ⊙ A(norm² ⊙ h1raw)) @ W2
    spmm_gemm<2><<<N_NODES / 4, 256, 0, stream>>>(
        h1raw, D, norm, row_start, cnt, csr_src, w2, nullptr, out, 128);
    // cols 0..63 = feats @ W0
    gemm_kernel<<<(N_NODES + 31) / 32, 256, 0, stream>>>(feats, w0, out);
}

// Round 8
// 450.889 us; speedup vs baseline: 1.5429x; 1.0479x over previous
//
#include <hip/hip_runtime.h>
#include <hip/hip_bf16.h>

#define N_NODES 100000
#define N_EDGES 1000000
#define D 64

// ---- histogram: ONE packed 64-bit atomic per edge ------------------------
// bits [63:40] = edge count, bits [39:0] = fixed-point sum of (w + 8) * 2^20
__global__ __launch_bounds__(256) void hist_kernel(
    const int* __restrict__ dst, const int* __restrict__ efeat,
    const float* __restrict__ edge_weight,
    unsigned long long* __restrict__ dc) {
    int e = blockIdx.x * 256 + threadIdx.x;
    if (e >= N_EDGES) return;
    int d = dst[e];
    int t = efeat[e] - 1;                  // 0..7
    float x = edge_weight[t] * 10.0f;
    float w = x > 0.0f ? x : 0.01f * x;    // leaky_relu, slope 0.01
    unsigned long long fx =
        (unsigned long long)__float2uint_rn((w + 8.0f) * 1048576.0f);
    atomicAdd(&dc[d], (1ull << 40) | fx);
}

// ---- unpack dc -> norm/cnt, allocate disjoint CSR ranges per block -------
__global__ __launch_bounds__(1024) void alloc_norm_kernel(
    const unsigned long long* __restrict__ dc,
    float* __restrict__ norm, int* __restrict__ cnt,
    int* __restrict__ row_start, int* __restrict__ cursor,
    int* __restrict__ total) {
    __shared__ int lds[1024];
    __shared__ int base_s;
    const int tid = threadIdx.x;
    const int i = blockIdx.x * 1024 + tid;
    int v = 0;
    if (i < N_NODES) {
        unsigned long long p = dc[i];
        v = (int)(p >> 40);
        float deg = (float)(p & ((1ull << 40) - 1)) * (1.0f / 1048576.0f)
                    - 8.0f * (float)v;
        deg = deg < 1.0f ? 1.0f : deg;
        norm[i] = rsqrtf(deg);
        cnt[i] = v;
    }
    lds[tid] = v;
    __syncthreads();
    for (int off = 1; off < 1024; off <<= 1) {
        int add = (tid >= off) ? lds[tid - off] : 0;
        __syncthreads();
        lds[tid] += add;
        __syncthreads();
    }
    if (tid == 1023) base_s = atomicAdd(total, lds[1023]);
    __syncthreads();
    if (i < N_NODES) {
        int ex = base_s + lds[tid] - v;    // block-exclusive + global base
        row_start[i] = ex;
        cursor[i] = ex;
    }
}

// ---- g1[n][k] = bf16(feats[n][k] * norm[n])  (12.8 MB gather table) ------
__global__ __launch_bounds__(256) void prep_g1(
    const float* __restrict__ feats, const float* __restrict__ norm,
    __hip_bfloat16* __restrict__ g1) {
    int i = blockIdx.x * 256 + threadIdx.x;      // group of 4 elements
    if (i >= N_NODES * D / 4) return;
    float4 v = ((const float4*)feats)[i];
    float ns = norm[i >> 4];                     // 16 groups per row
    __hip_bfloat162* p = (__hip_bfloat162*)g1 + i * 2;
    __hip_bfloat162 a, b;
    a.x = __float2bfloat16(v.x * ns); a.y = __float2bfloat16(v.y * ns);
    b.x = __float2bfloat16(v.z * ns); b.y = __float2bfloat16(v.w * ns);
    p[0] = a; p[1] = b;
}

// ---- scatter edges into CSR (order within a row irrelevant) ----
__global__ __launch_bounds__(256) void fill_csr_kernel(
    const int* __restrict__ src, const int* __restrict__ dst,
    int* __restrict__ cursor, int* __restrict__ csr_src) {
    int e = blockIdx.x * 256 + threadIdx.x;
    if (e >= N_EDGES) return;
    int pos = atomicAdd(&cursor[dst[e]], 1);
    csr_src[pos] = src[e];
}

// ---- fused bf16 gather-sum + GEMM epilogue -------------------------------
// One wave per destination node. G rows are PRE-SCALED (src-side norms folded
// in), so the inner loop is a pure sum: acc[lane] = sum_e G[s_e][lane].
// Epilogue: optionally save g2 = bf16(acc*norm^2) (spmm2's table), then
// out_row = (acc*norm) @ W via LDS.
template <int SAVE_G2>
__global__ __launch_bounds__(256) void spmm_gemm(
    const __hip_bfloat16* __restrict__ G,
    const float* __restrict__ norm,
    const int* __restrict__ row_start, const int* __restrict__ cnt,
    const int* __restrict__ csr_src,
    const float* __restrict__ W,
    __hip_bfloat16* __restrict__ g2,
    float* __restrict__ out, int col_off) {
    __shared__ float wt[D * D];          // wt[k*D + col]
    __shared__ float hs[4][D];
    const int tid = threadIdx.x;
    const int wv = tid >> 6;
    const int lane = tid & 63;
    const int node = blockIdx.x * 4 + wv;

    for (int i = tid; i < D * D; i += 256) wt[i] = W[i];

    const int beg = row_start[node];
    const int end = beg + cnt[node];
    float acc = 0.0f;
    int e = beg;
    for (; e + 3 < end; e += 4) {        // 4 independent gathers in flight
        int s0 = csr_src[e];
        int s1 = csr_src[e + 1];
        int s2 = csr_src[e + 2];
        int s3 = csr_src[e + 3];
        float v0 = __bfloat162float(G[(size_t)s0 * D + lane]);
        float v1 = __bfloat162float(G[(size_t)s1 * D + lane]);
        float v2 = __bfloat162float(G[(size_t)s2 * D + lane]);
        float v3 = __bfloat162float(G[(size_t)s3 * D + lane]);
        acc += (v0 + v1) + (v2 + v3);
    }
    for (; e < end; e++)
        acc += __bfloat162float(G[(size_t)csr_src[e] * D + lane]);

    const float nn = norm[node];
    if (SAVE_G2)
        g2[(size_t)node * D + lane] = __float2bfloat16(acc * nn * nn);
    hs[wv][lane] = acc * nn;             // dst-side norm folded here
    __syncthreads();                     // covers wt (cross-wave) + hs

    float o = 0.0f;
#pragma unroll 8
    for (int k = 0; k < D; k++)
        o = fmaf(hs[wv][k], wt[k * D + lane], o);
    out[(size_t)node * 192 + col_off + lane] = o;
}

// ---- plain GEMM for j=0: out[:,0:64] = feats @ W0 ----
__global__ __launch_bounds__(256) void gemm_kernel(
    const float* __restrict__ H,
    const float* __restrict__ W,
    float* __restrict__ out) {
    __shared__ float wt[D][D];
    __shared__ float ht[32][D];

    const int tid = threadIdx.x;
    const int node0 = blockIdx.x * 32;

    for (int i = tid; i < D * D; i += 256)
        ((float*)wt)[i] = W[i];

    for (int i = tid; i < 32 * D; i += 256) {
        int n = i >> 6;
        int k = i & 63;
        int node = node0 + n;
        ht[n][k] = (node < N_NODES) ? H[(size_t)node * D + k] : 0.0f;
    }
    __syncthreads();

    const int col = tid & 63;
    const int nb = tid >> 6;
    float acc[8];
#pragma unroll
    for (int r = 0; r < 8; r++) acc[r] = 0.0f;

    for (int k = 0; k < D; k++) {
        float wv = wt[k][col];
#pragma unroll
        for (int r = 0; r < 8; r++)
            acc[r] += ht[nb * 8 + r][k] * wv;
    }

#pragma unroll
    for (int r = 0; r < 8; r++) {
        int node = node0 + nb * 8 + r;
        if (node < N_NODES)
            out[(size_t)node * 192 + col] = acc[r];
    }
}

extern "C" void kernel_launch(void* const* d_in, const int* in_sizes, int n_in,
                              void* d_out, int out_size, void* d_ws, size_t ws_size,
                              hipStream_t stream) {
    const float* feats = (const float*)d_in[0];
    const float* ew    = (const float*)d_in[1];
    const float* w0    = (const float*)d_in[2];
    const float* w1    = (const float*)d_in[3];
    const float* w2    = (const float*)d_in[4];
    const int* src   = (const int*)d_in[5];
    const int* dst   = (const int*)d_in[6];
    const int* efeat = (const int*)d_in[7];
    float* out = (float*)d_out;

    // ws layout (~30.5 MiB): dc[N] u64 | total+pad | norm[N] | cnt[N] |
    // row_start[N] | cursor[N] | csr_src[1M] | g1[6.4M bf16] | g2[6.4M bf16]
    unsigned long long* dc = (unsigned long long*)d_ws;
    int* total     = (int*)(dc + N_NODES);
    float* norm    = (float*)(total + 2);
    int* cnt       = (int*)(norm + N_NODES);
    int* row_start = cnt + N_NODES;
    int* cursor    = row_start + N_NODES;
    int* csr_src   = cursor + N_NODES;
    __hip_bfloat16* g1 = (__hip_bfloat16*)(csr_src + N_EDGES);
    __hip_bfloat16* g2 = g1 + (size_t)N_NODES * D;

    // zero dc + total only (~800 KB)
    hipMemsetAsync(d_ws, 0, sizeof(unsigned long long) * N_NODES + 8, stream);

    hist_kernel<<<(N_EDGES + 255) / 256, 256, 0, stream>>>(dst, efeat, ew, dc);
    alloc_norm_kernel<<<(N_NODES + 1023) / 1024, 1024, 0, stream>>>(
        dc, norm, cnt, row_start, cursor, total);
    prep_g1<<<(N_NODES * D / 4 + 255) / 256, 256, 0, stream>>>(feats, norm, g1);
    fill_csr_kernel<<<(N_EDGES + 255) / 256, 256, 0, stream>>>(src, dst, cursor, csr_src);

    // cols 64..127 = (norm ⊙ A g1) @ W1, saving g2 = bf16(norm² ⊙ A g1)
    spmm_gemm<1><<<N_NODES / 4, 256, 0, stream>>>(
        g1, norm, row_start, cnt, csr_src, w1, g2, out, 64);
    // cols 128..191 = (norm ⊙ A g2) @ W2
    spmm_gemm<0><<<N_NODES / 4, 256, 0, stream>>>(
        g2, norm, row_start, cnt, csr_src, w2, nullptr, out, 128);
    // cols 0..63 = feats @ W0
    gemm_kernel<<<(N_NODES + 31) / 32, 256, 0, stream>>>(feats, w0, out);
}

// Round 9
// 425.315 us; speedup vs baseline: 1.6356x; 1.0601x over previous
//
#include <hip/hip_runtime.h>
#include <hip/hip_bf16.h>

#define N_NODES 100000
#define N_EDGES 1000000
#define D 64

// ---- histogram: ONE packed 64-bit atomic per edge ------------------------
// bits [63:40] = edge count, bits [39:0] = fixed-point sum of (w + 8) * 2^20
__global__ __launch_bounds__(256) void hist_kernel(
    const int* __restrict__ dst, const int* __restrict__ efeat,
    const float* __restrict__ edge_weight,
    unsigned long long* __restrict__ dc) {
    int e = blockIdx.x * 256 + threadIdx.x;
    if (e >= N_EDGES) return;
    int d = dst[e];
    int t = efeat[e] - 1;                  // 0..7
    float x = edge_weight[t] * 10.0f;
    float w = x > 0.0f ? x : 0.01f * x;    // leaky_relu, slope 0.01
    unsigned long long fx =
        (unsigned long long)__float2uint_rn((w + 8.0f) * 1048576.0f);
    atomicAdd(&dc[d], (1ull << 40) | fx);
}

// ---- unpack dc -> norm/cnt, allocate disjoint CSR ranges per block -------
__global__ __launch_bounds__(1024) void alloc_norm_kernel(
    const unsigned long long* __restrict__ dc,
    float* __restrict__ norm, int* __restrict__ cnt,
    int* __restrict__ row_start, int* __restrict__ cursor,
    int* __restrict__ total) {
    __shared__ int lds[1024];
    __shared__ int base_s;
    const int tid = threadIdx.x;
    const int i = blockIdx.x * 1024 + tid;
    int v = 0;
    if (i < N_NODES) {
        unsigned long long p = dc[i];
        v = (int)(p >> 40);
        float deg = (float)(p & ((1ull << 40) - 1)) * (1.0f / 1048576.0f)
                    - 8.0f * (float)v;
        deg = deg < 1.0f ? 1.0f : deg;
        norm[i] = rsqrtf(deg);
        cnt[i] = v;
    }
    lds[tid] = v;
    __syncthreads();
    for (int off = 1; off < 1024; off <<= 1) {
        int add = (tid >= off) ? lds[tid - off] : 0;
        __syncthreads();
        lds[tid] += add;
        __syncthreads();
    }
    if (tid == 1023) base_s = atomicAdd(total, lds[1023]);
    __syncthreads();
    if (i < N_NODES) {
        int ex = base_s + lds[tid] - v;    // block-exclusive + global base
        row_start[i] = ex;
        cursor[i] = ex;
    }
}

// ---- g1[n][k] = bf16(feats[n][k] * norm[n])  (12.8 MB gather table) ------
__global__ __launch_bounds__(256) void prep_g1(
    const float* __restrict__ feats, const float* __restrict__ norm,
    __hip_bfloat16* __restrict__ g1) {
    int i = blockIdx.x * 256 + threadIdx.x;      // group of 4 elements
    if (i >= N_NODES * D / 4) return;
    float4 v = ((const float4*)feats)[i];
    float ns = norm[i >> 4];                     // 16 groups per row
    __hip_bfloat162* p = (__hip_bfloat162*)g1 + i * 2;
    __hip_bfloat162 a, b;
    a.x = __float2bfloat16(v.x * ns); a.y = __float2bfloat16(v.y * ns);
    b.x = __float2bfloat16(v.z * ns); b.y = __float2bfloat16(v.w * ns);
    p[0] = a; p[1] = b;
}

// ---- scatter edges into CSR (order within a row irrelevant) ----
__global__ __launch_bounds__(256) void fill_csr_kernel(
    const int* __restrict__ src, const int* __restrict__ dst,
    int* __restrict__ cursor, int* __restrict__ csr_src) {
    int e = blockIdx.x * 256 + threadIdx.x;
    if (e >= N_EDGES) return;
    int pos = atomicAdd(&cursor[dst[e]], 1);
    csr_src[pos] = src[e];
}

// ---- fused bf16 gather-sum + GEMM epilogue, 2-edges-per-instruction ------
// One wave per destination node. lane = (half, feature-pair):
//   half = lane>>5 takes even/odd CSR slots; fp = lane&31 covers feats 2fp,2fp+1.
// Each gather is a dword (bfloat162) -> one wave instr covers 2 edges (256 B).
// Unroll 4 -> 8 edges in flight/wave. Halves combined via shfl_xor(32).
template <int SAVE_G2>
__global__ __launch_bounds__(256) void spmm_gemm(
    const __hip_bfloat16* __restrict__ G,
    const float* __restrict__ norm,
    const int* __restrict__ row_start, const int* __restrict__ cnt,
    const int* __restrict__ csr_src,
    const float* __restrict__ W,
    __hip_bfloat16* __restrict__ g2,
    float* __restrict__ out, int col_off) {
    __shared__ float wt[D * D];          // wt[k*D + col]
    __shared__ float hs[4][D];
    const int tid = threadIdx.x;
    const int wv = tid >> 6;
    const int lane = tid & 63;
    const int half = lane >> 5;          // edge parity
    const int fp = lane & 31;            // feature-pair index
    const int node = blockIdx.x * 4 + wv;

    for (int i = tid; i < D * D; i += 256) wt[i] = W[i];

    const unsigned int* Gp = (const unsigned int*)G;    // row = 32 dwords
    const int beg = row_start[node];
    const int end = beg + cnt[node];

    float accx = 0.0f, accy = 0.0f;
    int e = beg + half;                  // this half's first slot
    // main loop: 4 independent dword gathers (= 8 edges/wave) in flight
    for (; e + 6 < end; e += 8) {
        int s0 = csr_src[e];
        int s1 = csr_src[e + 2];
        int s2 = csr_src[e + 4];
        int s3 = csr_src[e + 6];
        unsigned int p0 = Gp[(size_t)s0 * 32 + fp];
        unsigned int p1 = Gp[(size_t)s1 * 32 + fp];
        unsigned int p2 = Gp[(size_t)s2 * 32 + fp];
        unsigned int p3 = Gp[(size_t)s3 * 32 + fp];
        float x0 = __uint_as_float(p0 << 16) + __uint_as_float(p1 << 16);
        float x1 = __uint_as_float(p2 << 16) + __uint_as_float(p3 << 16);
        float y0 = __uint_as_float(p0 & 0xffff0000u) + __uint_as_float(p1 & 0xffff0000u);
        float y1 = __uint_as_float(p2 & 0xffff0000u) + __uint_as_float(p3 & 0xffff0000u);
        accx += x0 + x1;
        accy += y0 + y1;
    }
    for (; e < end; e += 2) {            // tail (this half's parity slots)
        unsigned int p = Gp[(size_t)csr_src[e] * 32 + fp];
        accx += __uint_as_float(p << 16);
        accy += __uint_as_float(p & 0xffff0000u);
    }
    // combine the two halves (lane l and l^32 hold the same feature pair)
    accx += __shfl_xor(accx, 32);
    accy += __shfl_xor(accy, 32);

    const float nn = norm[node];
    if (half == 0) {
        if (SAVE_G2) {
            __hip_bfloat162 hb;
            hb.x = __float2bfloat16(accx * nn * nn);
            hb.y = __float2bfloat16(accy * nn * nn);
            ((__hip_bfloat162*)g2)[(size_t)node * 32 + fp] = hb;
        }
        hs[wv][2 * fp]     = accx * nn;  // dst-side norm folded here
        hs[wv][2 * fp + 1] = accy * nn;
    }
    __syncthreads();                     // covers wt (cross-wave) + hs

    float o = 0.0f;
#pragma unroll 8
    for (int k = 0; k < D; k++)
        o = fmaf(hs[wv][k], wt[k * D + lane], o);
    out[(size_t)node * 192 + col_off + lane] = o;
}

// ---- plain GEMM for j=0: out[:,0:64] = feats @ W0 ----
__global__ __launch_bounds__(256) void gemm_kernel(
    const float* __restrict__ H,
    const float* __restrict__ W,
    float* __restrict__ out) {
    __shared__ float wt[D][D];
    __shared__ float ht[32][D];

    const int tid = threadIdx.x;
    const int node0 = blockIdx.x * 32;

    for (int i = tid; i < D * D; i += 256)
        ((float*)wt)[i] = W[i];

    for (int i = tid; i < 32 * D; i += 256) {
        int n = i >> 6;
        int k = i & 63;
        int node = node0 + n;
        ht[n][k] = (node < N_NODES) ? H[(size_t)node * D + k] : 0.0f;
    }
    __syncthreads();

    const int col = tid & 63;
    const int nb = tid >> 6;
    float acc[8];
#pragma unroll
    for (int r = 0; r < 8; r++) acc[r] = 0.0f;

    for (int k = 0; k < D; k++) {
        float wv = wt[k][col];
#pragma unroll
        for (int r = 0; r < 8; r++)
            acc[r] += ht[nb * 8 + r][k] * wv;
    }

#pragma unroll
    for (int r = 0; r < 8; r++) {
        int node = node0 + nb * 8 + r;
        if (node < N_NODES)
            out[(size_t)node * 192 + col] = acc[r];
    }
}

extern "C" void kernel_launch(void* const* d_in, const int* in_sizes, int n_in,
                              void* d_out, int out_size, void* d_ws, size_t ws_size,
                              hipStream_t stream) {
    const float* feats = (const float*)d_in[0];
    const float* ew    = (const float*)d_in[1];
    const float* w0    = (const float*)d_in[2];
    const float* w1    = (const float*)d_in[3];
    const float* w2    = (const float*)d_in[4];
    const int* src   = (const int*)d_in[5];
    const int* dst   = (const int*)d_in[6];
    const int* efeat = (const int*)d_in[7];
    float* out = (float*)d_out;

    // ws layout (~30.5 MiB): dc[N] u64 | total+pad | norm[N] | cnt[N] |
    // row_start[N] | cursor[N] | csr_src[1M] | g1[6.4M bf16] | g2[6.4M bf16]
    unsigned long long* dc = (unsigned long long*)d_ws;
    int* total     = (int*)(dc + N_NODES);
    float* norm    = (float*)(total + 2);
    int* cnt       = (int*)(norm + N_NODES);
    int* row_start = cnt + N_NODES;
    int* cursor    = row_start + N_NODES;
    int* csr_src   = cursor + N_NODES;
    __hip_bfloat16* g1 = (__hip_bfloat16*)(csr_src + N_EDGES);
    __hip_bfloat16* g2 = g1 + (size_t)N_NODES * D;

    // zero dc + total only (~800 KB)
    hipMemsetAsync(d_ws, 0, sizeof(unsigned long long) * N_NODES + 8, stream);

    hist_kernel<<<(N_EDGES + 255) / 256, 256, 0, stream>>>(dst, efeat, ew, dc);
    alloc_norm_kernel<<<(N_NODES + 1023) / 1024, 1024, 0, stream>>>(
        dc, norm, cnt, row_start, cursor, total);
    prep_g1<<<(N_NODES * D / 4 + 255) / 256, 256, 0, stream>>>(feats, norm, g1);
    fill_csr_kernel<<<(N_EDGES + 255) / 256, 256, 0, stream>>>(src, dst, cursor, csr_src);

    // cols 64..127 = (norm ⊙ A g1) @ W1, saving g2 = bf16(norm² ⊙ A g1)
    spmm_gemm<1><<<N_NODES / 4, 256, 0, stream>>>(
        g1, norm, row_start, cnt, csr_src, w1, g2, out, 64);
    // cols 128..191 = (norm ⊙ A g2) @ W2
    spmm_gemm<0><<<N_NODES / 4, 256, 0, stream>>>(
        g2, norm, row_start, cnt, csr_src, w2, nullptr, out, 128);
    // cols 0..63 = feats @ W0
    gemm_kernel<<<(N_NODES + 31) / 32, 256, 0, stream>>>(feats, w0, out);
}